// Round 2
// baseline (373.412 us; speedup 1.0000x reference)
//
#include <hip/hip_runtime.h>

// Normalized correlation layer, MI355X.
// B=8 H=W=32 C=64 K=5 PAD=2.
// out[b,r,w, c*160 + e*32 + f] =
//   sum_p P1n[b,r,w,c,p] * P2n[b,r+e,f,c,p]
// with P1 patches from x1 padded (2,2)x(2,2), P2 patches from x2 padded
// (4,4)x(2,2) with list-row remap lr -> (lr<=33 ? lr : lr-2), both
// zero-mean/unit-population-std normalized over the 25 patch elements.
// Identity used: sum (a-m1)(b-m2) = sum a*b - 25*m1*m2, then * (1/s1)(1/s2).

namespace {

constexpr int OUTC = 64 * 5 * 32; // 10240

__global__ __launch_bounds__(256)
void ncc_kernel(const float* __restrict__ in1, const float* __restrict__ in2,
                float* __restrict__ out) {
    // block = (b, r, cpair); c0 = cpair*2
    const int bid = blockIdx.x;
    const int cpair = bid & 31;
    const int r = (bid >> 5) & 31;
    const int b = bid >> 10;
    const int c0 = cpair * 2;

    __shared__ __align__(16) float x1s[2][5][36];  // rows r..r+4 of x1pad
    __shared__ __align__(16) float x2s[2][9][36];  // rows r..r+8 of x2pad
    __shared__ float m1s[2][32], i1s[2][32];       // P1 stats per w
    __shared__ float m2s[2][5][32], i2s[2][5][32]; // P2 stats per (e,f)

    const int tid = threadIdx.x;

    // ---- stage x1pad rows r..r+4, cols 0..35, channels c0,c0+1 ----
    for (int idx = tid; idx < 2 * 5 * 36; idx += 256) {
        const int c2 = idx / 180;
        const int rem = idx - c2 * 180;
        const int i = rem / 36;
        const int pc = rem - i * 36;
        const int ir = r + i - 2;   // x1pad row -> input row
        const int ic = pc - 2;
        float v = 0.f;
        if (ir >= 0 && ir < 32 && ic >= 0 && ic < 32)
            v = in1[((b * 32 + ir) * 32 + ic) * 64 + c0 + c2];
        x1s[c2][i][pc] = v;
    }
    // ---- stage x2pad rows r..r+8 (top/bottom pad = 4 rows) ----
    for (int idx = tid; idx < 2 * 9 * 36; idx += 256) {
        const int c2 = idx / 324;
        const int rem = idx - c2 * 324;
        const int k = rem / 36;
        const int pc = rem - k * 36;
        const int ir = r + k - 4;   // x2pad row -> input row
        const int ic = pc - 2;
        float v = 0.f;
        if (ir >= 0 && ir < 32 && ic >= 0 && ic < 32)
            v = in2[((b * 32 + ir) * 32 + ic) * 64 + c0 + c2];
        x2s[c2][k][pc] = v;
    }
    __syncthreads();

    // ---- P1 patch stats per (c2, w) ----
    if (tid < 64) {
        const int c2 = tid >> 5, w = tid & 31;
        float s = 0.f, ss = 0.f;
        #pragma unroll
        for (int i = 0; i < 5; ++i)
            #pragma unroll
            for (int j = 0; j < 5; ++j) {
                const float v = x1s[c2][i][w + j];
                s += v; ss += v * v;
            }
        const float m = s * (1.0f / 25.0f);
        const float var = ss * (1.0f / 25.0f) - m * m;
        m1s[c2][w] = m;
        i1s[c2][w] = 1.0f / sqrtf(fmaxf(var, 1e-30f));
    }
    // ---- P2 patch stats per (c2, e, f); row remap lr<=33?lr:lr-2 ----
    for (int t = tid; t < 320; t += 256) {
        const int c2 = t / 160;
        const int rem = t - c2 * 160;
        const int e = rem >> 5;
        const int f = rem & 31;
        const int bb = (r + e <= 33) ? e : e - 2; // row base rel. to r
        float s = 0.f, ss = 0.f;
        #pragma unroll
        for (int i = 0; i < 5; ++i)
            #pragma unroll
            for (int j = 0; j < 5; ++j) {
                const float v = x2s[c2][bb + i][f + j];
                s += v; ss += v * v;
            }
        const float m = s * (1.0f / 25.0f);
        const float var = ss * (1.0f / 25.0f) - m * m;
        m2s[c2][e][f] = m;
        i2s[c2][e][f] = 1.0f / sqrtf(fmaxf(var, 1e-30f));
    }
    __syncthreads();

    // ---- main correlation: lane = (c2, f), wave owns 8 w values ----
    const int lane = tid & 63;
    const int wave = tid >> 6;
    const int c2 = lane >> 5;
    const int f = lane & 31;
    const int wbase = wave * 8;

    int base_e[5];
    #pragma unroll
    for (int e = 0; e < 5; ++e) base_e[e] = (r + e <= 33) ? e : e - 2;

    float acc[8][5];
    #pragma unroll
    for (int wi = 0; wi < 8; ++wi)
        #pragma unroll
        for (int e = 0; e < 5; ++e) acc[wi][e] = 0.f;

    #pragma unroll
    for (int i = 0; i < 5; ++i) {
        // 12-wide x1 row segment (cols wbase..wbase+11), 16B-aligned
        float A[12];
        const float4* ap = reinterpret_cast<const float4*>(&x1s[c2][i][wbase]);
        const float4 a0 = ap[0], a1 = ap[1], a2 = ap[2];
        A[0] = a0.x; A[1] = a0.y; A[2]  = a0.z; A[3]  = a0.w;
        A[4] = a1.x; A[5] = a1.y; A[6]  = a1.z; A[7]  = a1.w;
        A[8] = a2.x; A[9] = a2.y; A[10] = a2.z; A[11] = a2.w;

        float Br[5][5];
        #pragma unroll
        for (int e = 0; e < 5; ++e) {
            const float* bp = &x2s[c2][base_e[e] + i][f];
            #pragma unroll
            for (int j = 0; j < 5; ++j) Br[e][j] = bp[j];
        }

        #pragma unroll
        for (int j = 0; j < 5; ++j)
            #pragma unroll
            for (int e = 0; e < 5; ++e)
                #pragma unroll
                for (int wi = 0; wi < 8; ++wi)
                    acc[wi][e] += A[wi + j] * Br[e][j];
    }

    // ---- epilogue: normalization correction + coalesced stores ----
    float m2v[5], i2v[5];
    #pragma unroll
    for (int e = 0; e < 5; ++e) { m2v[e] = m2s[c2][e][f]; i2v[e] = i2s[c2][e][f]; }

    const int outrow = (b * 32 + r) * 32;             // (b,r) row of W entries
    float* op0 = out + (size_t)outrow * OUTC + (c0 + c2) * 160 + f;
    #pragma unroll
    for (int wi = 0; wi < 8; ++wi) {
        const int w = wbase + wi;
        const float m1 = m1s[c2][w];
        const float i1 = i1s[c2][w];
        float* op = op0 + (size_t)w * OUTC;
        #pragma unroll
        for (int e = 0; e < 5; ++e) {
            op[e * 32] = (acc[wi][e] - 25.0f * m1 * m2v[e]) * (i1 * i2v[e]);
        }
    }
}

} // namespace

extern "C" void kernel_launch(void* const* d_in, const int* in_sizes, int n_in,
                              void* d_out, int out_size, void* d_ws, size_t ws_size,
                              hipStream_t stream) {
    const float* in1 = (const float*)d_in[0];
    const float* in2 = (const float*)d_in[1];
    float* out = (float*)d_out;
    // grid = B(8) * r(32) * cpair(32) = 8192 blocks
    hipLaunchKernelGGL(ncc_kernel, dim3(8192), dim3(256), 0, stream, in1, in2, out);
}